// Round 1
// 192.024 us; speedup vs baseline: 1.1313x; 1.1313x over previous
//
#include <hip/hip_runtime.h>
#include <math.h>

#define CI 12
#define NHID 15
#define NBLK 6144                 // 8*3*16*16 image blocks of 32x32
#define NPIX (NBLK * 1024)

typedef int i32x4 __attribute__((ext_vector_type(4)));

// f32 pair -> packed f16 (RTZ) via v_cvt_pkrtz_f16_f32 (1 VALU inst)
static __device__ __forceinline__ int h2pack(float lo, float hi) {
    auto h = __builtin_amdgcn_cvt_pkrtz(lo, hi);   // half2
    int r;
    __builtin_memcpy(&r, &h, 4);
    return r;
}

// ---- hand-scheduled hot-loop asm ------------------------------------------
// MLP runs in f16 (10-bit mantissa; strictly finer than the old bf16 path).
// Fixed VGPRs (clobbered): Z=v[32:35], BA=v[36:39], BB=v[40:43], BC=v[44:47],
// BD=v[48:51], DA=v[52:55], DB=v[56:59], DC=v[60:63], DD=v[64:67], tmp v68/v69.
// Weights: 16 AGPR quads via operands.
// Activation+repack per chain (4 f32 -> 2 packed-f16 words), 6 VALU insts:
//   cvt_pkrtz x2 (f32->f16x2), pk_mul_f16 x2 (0.01*x), pk_max_f16 x2 (leaky).
// s21 = 0x211F211F = f16(0.01) broadcast.
// Hazard spacing: min MFMA-D -> first-VALU-read gap ~36 cy in-loop; the
// previous kernel's epilogue proved ~23 cy safe, so margin retained.
#define LKA \
  "v_cvt_pkrtz_f16_f32 v36, v52, v53\n" \
  "v_cvt_pkrtz_f16_f32 v37, v54, v55\n" \
  "v_pk_mul_f16 v68, s21, v36\n" \
  "v_pk_mul_f16 v69, s21, v37\n" \
  "v_pk_max_f16 v36, v36, v68\n" \
  "v_pk_max_f16 v37, v37, v69\n"
#define LKB \
  "v_cvt_pkrtz_f16_f32 v40, v56, v57\n" \
  "v_cvt_pkrtz_f16_f32 v41, v58, v59\n" \
  "v_pk_mul_f16 v68, s21, v40\n" \
  "v_pk_mul_f16 v69, s21, v41\n" \
  "v_pk_max_f16 v40, v40, v68\n" \
  "v_pk_max_f16 v41, v41, v69\n"
#define LKC \
  "v_cvt_pkrtz_f16_f32 v44, v60, v61\n" \
  "v_cvt_pkrtz_f16_f32 v45, v62, v63\n" \
  "v_pk_mul_f16 v68, s21, v44\n" \
  "v_pk_mul_f16 v69, s21, v45\n" \
  "v_pk_max_f16 v44, v44, v68\n" \
  "v_pk_max_f16 v45, v45, v69\n"
#define LKD \
  "v_cvt_pkrtz_f16_f32 v48, v64, v65\n" \
  "v_cvt_pkrtz_f16_f32 v49, v66, v67\n" \
  "v_pk_mul_f16 v68, s21, v48\n" \
  "v_pk_mul_f16 v69, s21, v49\n" \
  "v_pk_max_f16 v48, v48, v68\n" \
  "v_pk_max_f16 v49, v49, v69\n"

#define MFA(w) "v_mfma_f32_16x16x32_f16 v[52:55], %[" w "], v[36:39], v[32:35]\n"
#define MFB(w) "v_mfma_f32_16x16x32_f16 v[56:59], %[" w "], v[40:43], v[32:35]\n"
#define MFC(w) "v_mfma_f32_16x16x32_f16 v[60:63], %[" w "], v[44:47], v[32:35]\n"
#define MFD(w) "v_mfma_f32_16x16x32_f16 v[64:67], %[" w "], v[48:51], v[32:35]\n"

#define LAYER(w) LKA LKB MFA(w) LKC MFB(w) LKD MFC(w) "s_nop 1\n" MFD(w)

__global__ __launch_bounds__(256, 3) void codec_main(
    const float* __restrict__ x,
    const float* __restrict__ Wh,   // [15][12][12]
    const float* __restrict__ bh,   // [15][12]
    const float* __restrict__ Wo,   // [12]
    const float* __restrict__ bo,   // [1]
    float* __restrict__ out,        // [1 + NPIX]
    float* __restrict__ loss_acc)   // [1] pre-zeroed
{
    __shared__ float tile[36 * 37]; // 32x32 + 2-halo, +1 col pad
    __shared__ float stage[4][256]; // per-wave delta staging
    __shared__ float wsum[4];

    const int n    = blockIdx.x;
    const int tid  = threadIdx.x;   // 0..255
    const int lane = tid & 63;
    const int wv   = tid >> 6;      // wave 0..3
    const int t    = lane & 15;
    const int q    = lane >> 4;

    // ---- stage image block into LDS (zero halo) ----
    {
        const int col = tid & 31;
        const int r0  = tid >> 5;
        #pragma unroll
        for (int i = 0; i < 6; ++i) {
            int idx = tid + i * 256;
            if (idx < 36 * 37) tile[idx] = 0.0f;
        }
        __syncthreads();
        const int bc  = n >> 8;
        const int blk = n & 255;
        const int by  = blk >> 4;
        const int bx  = blk & 15;
        #pragma unroll
        for (int p = 0; p < 4; ++p) {
            const int row = r0 + 8 * p;
            tile[(row + 2) * 37 + col + 2] =
                x[((size_t)bc * 512 + (size_t)(by * 32 + row)) * 512
                  + (size_t)(bx * 32 + col)];
        }
        __syncthreads();
    }

    // ---- weight A-frags (sparse-K, proven R4): lane 16q+t = A[m=t][k=8q+j]
    i32x4 wq[16];
    const bool wok = (t < CI) && (q < 3);
    #pragma unroll
    for (int l = 0; l < NHID; ++l) {
        float4 w = {0.f, 0.f, 0.f, 0.f};
        float  b = 0.f;
        if (wok) w = *(const float4*)(Wh + l * (CI * CI) + t * CI + 4 * q);
        if (wok && q == 0) b = bh[l * CI + t];
        wq[l] = (i32x4){ h2pack(w.x, w.y), h2pack(w.z, w.w),
                         h2pack(b, 0.f), 0 };
    }
    {
        float4 w = {0.f, 0.f, 0.f, 0.f};
        float  b = 0.f;
        if (t == 0 && q < 3) w = *(const float4*)(Wo + 4 * q);
        if (t == 0 && q == 0) b = bo[0];
        wq[15] = (i32x4){ h2pack(w.x, w.y), h2pack(w.z, w.w),
                          h2pack(b, 0.f), 0 };
    }

    // ---- per-lane feature offsets (elements): channel c=4q+r at (dy,dx) ----
    const int sh8  = q * 8;
    const int off0 = (int)(signed char)((0x00DCB8B4u >> sh8) & 0xFFu);
    const int off1 = (int)(signed char)((0x00DDD9B5u >> sh8) & 0xFFu);
    const int off2 = (int)(signed char)((0x00FEDAB6u >> sh8) & 0xFFu);
    const int off3 = (int)(signed char)((0x00FFDBB7u >> sh8) & 0xFFu);

    const int biasreg = (q == 0) ? 0x00003C00 : 0;   // k=4 slot = f16(1.0)
    int e = (wv * 8 + 2) * 37 + (t + 2);             // row 8wv, half 0

    float d2 = 0.0f;
    #pragma unroll 1
    for (int yi = 0; yi < 4; ++yi) {
        // chains: A=(row r,half0) B=(r,half1) C=(r+1,half0) D=(r+1,half1)
        const int faA0 = h2pack(tile[e + off0],      tile[e + off1]);
        const int faA1 = h2pack(tile[e + off2],      tile[e + off3]);
        const int fbA0 = h2pack(tile[e + off0 + 16], tile[e + off1 + 16]);
        const int fbA1 = h2pack(tile[e + off2 + 16], tile[e + off3 + 16]);
        const int fcA0 = h2pack(tile[e + off0 + 37], tile[e + off1 + 37]);
        const int fcA1 = h2pack(tile[e + off2 + 37], tile[e + off3 + 37]);
        const int fdA0 = h2pack(tile[e + off0 + 53], tile[e + off1 + 53]);
        const int fdA1 = h2pack(tile[e + off2 + 53], tile[e + off3 + 53]);
        const float vA = tile[e], vB = tile[e + 16];
        const float vC = tile[e + 37], vD = tile[e + 53];

        float pA, pB, pC, pD;
        asm volatile(
            "s_mov_b32 s21, 0x211f211f\n"
            "v_mov_b32 v32, 0\n" "v_mov_b32 v33, 0\n"
            "v_mov_b32 v34, 0\n" "v_mov_b32 v35, 0\n"
            "v_mov_b32 v36, %[fa0]\n" "v_mov_b32 v37, %[fa1]\n"
            "v_mov_b32 v38, %[bias]\n" "v_mov_b32 v39, 0\n"
            "v_mov_b32 v40, %[fb0]\n" "v_mov_b32 v41, %[fb1]\n"
            "v_mov_b32 v42, %[bias]\n" "v_mov_b32 v43, 0\n"
            "v_mov_b32 v44, %[fc0]\n" "v_mov_b32 v45, %[fc1]\n"
            "v_mov_b32 v46, %[bias]\n" "v_mov_b32 v47, 0\n"
            "v_mov_b32 v48, %[fd0]\n" "v_mov_b32 v49, %[fd1]\n"
            "v_mov_b32 v50, %[bias]\n" "v_mov_b32 v51, 0\n"
            MFA("w0") MFB("w0") MFC("w0") MFD("w0")
            "s_nop 7\n" "s_nop 7\n" "s_nop 7\n"
            LAYER("w1")  LAYER("w2")  LAYER("w3")  LAYER("w4")
            LAYER("w5")  LAYER("w6")  LAYER("w7")  LAYER("w8")
            LAYER("w9")  LAYER("w10") LAYER("w11") LAYER("w12")
            LAYER("w13") LAYER("w14") LAYER("w15")
            "v_mov_b32 %[pA], v52\n"
            "s_nop 1\n"
            "v_mov_b32 %[pB], v56\n"
            "s_nop 7\n" "s_nop 7\n"
            "v_mov_b32 %[pC], v60\n"
            "s_nop 3\n"
            "v_mov_b32 %[pD], v64\n"
            : [pA] "=v"(pA), [pB] "=v"(pB), [pC] "=v"(pC), [pD] "=v"(pD)
            : [w0] "a"(wq[0]),  [w1] "a"(wq[1]),  [w2] "a"(wq[2]),
              [w3] "a"(wq[3]),  [w4] "a"(wq[4]),  [w5] "a"(wq[5]),
              [w6] "a"(wq[6]),  [w7] "a"(wq[7]),  [w8] "a"(wq[8]),
              [w9] "a"(wq[9]),  [w10] "a"(wq[10]), [w11] "a"(wq[11]),
              [w12] "a"(wq[12]), [w13] "a"(wq[13]), [w14] "a"(wq[14]),
              [w15] "a"(wq[15]),
              [fa0] "v"(faA0), [fa1] "v"(faA1), [fb0] "v"(fbA0), [fb1] "v"(fbA1),
              [fc0] "v"(fcA0), [fc1] "v"(fcA1), [fd0] "v"(fdA0), [fd1] "v"(fdA1),
              [bias] "v"(biasreg)
            : "s21",
              "v32","v33","v34","v35","v36","v37","v38","v39",
              "v40","v41","v42","v43","v44","v45","v46","v47",
              "v48","v49","v50","v51","v52","v53","v54","v55",
              "v56","v57","v58","v59","v60","v61","v62","v63",
              "v64","v65","v66","v67","v68","v69");

        if (lane < 16) {                   // D row 0 = prediction, lanes 0..15
            const float qA = fminf(fmaxf(pA, -1.0f), 1.0f);
            const float uA = vA - qA + 1.0f;
            const float dA = uA - ((uA < 2.0f) ? 1.0f : 3.0f); // fmod(u,2)-1
            const float qB = fminf(fmaxf(pB, -1.0f), 1.0f);
            const float uB = vB - qB + 1.0f;
            const float dB = uB - ((uB < 2.0f) ? 1.0f : 3.0f);
            const float qC = fminf(fmaxf(pC, -1.0f), 1.0f);
            const float uC = vC - qC + 1.0f;
            const float dC = uC - ((uC < 2.0f) ? 1.0f : 3.0f);
            const float qD = fminf(fmaxf(pD, -1.0f), 1.0f);
            const float uD = vD - qD + 1.0f;
            const float dD = uD - ((uD < 2.0f) ? 1.0f : 3.0f);
            const int r = 2 * yi;
            stage[wv][r * 32 + t]            = dA;
            stage[wv][r * 32 + 16 + t]       = dB;
            stage[wv][(r + 1) * 32 + t]      = dC;
            stage[wv][(r + 1) * 32 + 16 + t] = dD;
            d2 = fmaf(dA, dA, fmaf(dB, dB, fmaf(dC, dC, fmaf(dD, dD, d2))));
        }
        e += 74;                            // two rows
    }

    // ---- coalesced delta store: wave's 256 floats = rows [8wv, 8wv+8) ----
    float* outp = out + 1 + (size_t)n * 1024 + wv * 256;
    #pragma unroll
    for (int j = 0; j < 4; ++j)
        outp[j * 64 + lane] = stage[wv][j * 64 + lane];

    // ---- loss reduction (d2 nonzero only in lanes 0..15) ----
    #pragma unroll
    for (int off = 8; off > 0; off >>= 1) d2 += __shfl_down(d2, off, 64);
    if (lane == 0) wsum[wv] = d2;
    __syncthreads();
    if (tid == 0) atomicAdd(loss_acc, wsum[0] + wsum[1] + wsum[2] + wsum[3]);
}

__global__ void codec_loss(const float* __restrict__ acc, float* __restrict__ out)
{
    out[0] = 255.0f * sqrtf(acc[0] / (float)NPIX);
}

extern "C" void kernel_launch(void* const* d_in, const int* in_sizes, int n_in,
                              void* d_out, int out_size, void* d_ws, size_t ws_size,
                              hipStream_t stream)
{
    const float* x  = (const float*)d_in[0];
    const float* Wh = (const float*)d_in[1];
    const float* bh = (const float*)d_in[2];
    const float* Wo = (const float*)d_in[3];
    const float* bo = (const float*)d_in[4];
    float* out = (float*)d_out;
    float* acc = (float*)d_ws;

    hipMemsetAsync(acc, 0, sizeof(float), stream);   // graph-capture safe
    codec_main<<<NBLK, 256, 0, stream>>>(x, Wh, bh, Wo, bo, out, acc);
    codec_loss<<<1, 1, 0, stream>>>(acc, out);
}

// Round 2
// 183.684 us; speedup vs baseline: 1.1827x; 1.0454x over previous
//
#include <hip/hip_runtime.h>
#include <math.h>

#define CI 12
#define NHID 15
#define NBLK 6144                 // 8*3*16*16 image blocks of 32x32
#define NPIX (NBLK * 1024)

typedef int i32x2 __attribute__((ext_vector_type(2)));

// f32 pair -> packed f16 (RTZ) via v_cvt_pkrtz_f16_f32 (1 VALU inst)
static __device__ __forceinline__ int h2pack(float lo, float hi) {
    auto h = __builtin_amdgcn_cvt_pkrtz(lo, hi);   // half2
    int r;
    __builtin_memcpy(&r, &h, 4);
    return r;
}

// ---- hand-scheduled hot-loop asm ------------------------------------------
// MLP in f16 via v_mfma_f32_16x16x16_f16 (A = 2 regs -> 32 AGPRs total for
// 16 layers, vs 64 with the x32 shape; frees occupancy 3 -> 4 waves/SIMD).
// K map: lane 16q+t holds A[m=t][k=4q+j] / B[k=4q+j][n=t], j=0..3.
//   k 0..11  = the 12 channels (q=0..2)
//   k 12     = bias slot: A[m][12]=bh[m], plus identity A[12][12]=1.0 so
//              D[12][*]=1.0 every layer -> activation regenerates the 1.0
//              bias operand for the next layer at zero VALU cost.
//   k 13..15 = zero
// Fixed VGPRs (clobbered): Z=v[32:35], BA=v[36:37], BB=v[38:39], BC=v[40:41],
// BD=v[42:43], DA=v[44:47], DB=v[48:51], DC=v[52:55], DD=v[56:59], tmp v60/61.
// Activation per chain: cvt_pkrtz x2, pk_mul x2 (0.01x), pk_max x2 (leaky).
// s21 = 0x211F211F = f16(0.01) broadcast.
#define LKA \
  "v_cvt_pkrtz_f16_f32 v36, v44, v45\n" \
  "v_cvt_pkrtz_f16_f32 v37, v46, v47\n" \
  "v_pk_mul_f16 v60, s21, v36\n" \
  "v_pk_mul_f16 v61, s21, v37\n" \
  "v_pk_max_f16 v36, v36, v60\n" \
  "v_pk_max_f16 v37, v37, v61\n"
#define LKB \
  "v_cvt_pkrtz_f16_f32 v38, v48, v49\n" \
  "v_cvt_pkrtz_f16_f32 v39, v50, v51\n" \
  "v_pk_mul_f16 v60, s21, v38\n" \
  "v_pk_mul_f16 v61, s21, v39\n" \
  "v_pk_max_f16 v38, v38, v60\n" \
  "v_pk_max_f16 v39, v39, v61\n"
#define LKC \
  "v_cvt_pkrtz_f16_f32 v40, v52, v53\n" \
  "v_cvt_pkrtz_f16_f32 v41, v54, v55\n" \
  "v_pk_mul_f16 v60, s21, v40\n" \
  "v_pk_mul_f16 v61, s21, v41\n" \
  "v_pk_max_f16 v40, v40, v60\n" \
  "v_pk_max_f16 v41, v41, v61\n"
#define LKD \
  "v_cvt_pkrtz_f16_f32 v42, v56, v57\n" \
  "v_cvt_pkrtz_f16_f32 v43, v58, v59\n" \
  "v_pk_mul_f16 v60, s21, v42\n" \
  "v_pk_mul_f16 v61, s21, v43\n" \
  "v_pk_max_f16 v42, v42, v60\n" \
  "v_pk_max_f16 v43, v43, v61\n"

#define MFA(w) "v_mfma_f32_16x16x16_f16 v[44:47], %[" w "], v[36:37], v[32:35]\n"
#define MFB(w) "v_mfma_f32_16x16x16_f16 v[48:51], %[" w "], v[38:39], v[32:35]\n"
#define MFC(w) "v_mfma_f32_16x16x16_f16 v[52:55], %[" w "], v[40:41], v[32:35]\n"
#define MFD(w) "v_mfma_f32_16x16x16_f16 v[56:59], %[" w "], v[42:43], v[32:35]\n"

#define LAYER(w) LKA LKB MFA(w) LKC MFB(w) LKD MFC(w) "s_nop 1\n" MFD(w)

__global__ __launch_bounds__(256, 4) void codec_main(
    const float* __restrict__ x,
    const float* __restrict__ Wh,   // [15][12][12]
    const float* __restrict__ bh,   // [15][12]
    const float* __restrict__ Wo,   // [12]
    const float* __restrict__ bo,   // [1]
    float* __restrict__ out,        // [1 + NPIX]
    float* __restrict__ loss_acc)   // [1] pre-zeroed
{
    __shared__ float tile[36 * 37]; // 32x32 + 2-halo, +1 col pad
    __shared__ float stage[4][256]; // per-wave delta staging
    __shared__ float wsum[4];

    const int n    = blockIdx.x;
    const int tid  = threadIdx.x;   // 0..255
    const int lane = tid & 63;
    const int wv   = tid >> 6;      // wave 0..3
    const int t    = lane & 15;
    const int q    = lane >> 4;

    // ---- stage image block into LDS (zero halo) ----
    {
        const int col = tid & 31;
        const int r0  = tid >> 5;
        #pragma unroll
        for (int i = 0; i < 6; ++i) {
            int idx = tid + i * 256;
            if (idx < 36 * 37) tile[idx] = 0.0f;
        }
        __syncthreads();
        const int bc  = n >> 8;
        const int blk = n & 255;
        const int by  = blk >> 4;
        const int bx  = blk & 15;
        #pragma unroll
        for (int p = 0; p < 4; ++p) {
            const int row = r0 + 8 * p;
            tile[(row + 2) * 37 + col + 2] =
                x[((size_t)bc * 512 + (size_t)(by * 32 + row)) * 512
                  + (size_t)(bx * 32 + col)];
        }
        __syncthreads();
    }

    // ---- weight A-frags (K=16): lane 16q+t = A[m=t][k=4q+j], j=0..3 ----
    // q<3: channels; q==3: word0 = pack(bias, 0) (k=12), word1 = 0;
    // q==3,t==12 (hidden layers): identity 1.0 to self-propagate bias slot.
    i32x2 wq[16];
    #pragma unroll
    for (int l = 0; l < NHID; ++l) {
        int w0 = 0, w1 = 0;
        if (q < 3 && t < CI) {
            float4 w = *(const float4*)(Wh + l * (CI * CI) + t * CI + 4 * q);
            w0 = h2pack(w.x, w.y);
            w1 = h2pack(w.z, w.w);
        }
        if (q == 3 && t < CI)  w0 = h2pack(bh[l * CI + t], 0.f);
        if (q == 3 && t == CI) w0 = 0x3C00;            // A[12][12] = 1.0
        wq[l] = (i32x2){ w0, w1 };
    }
    {
        int w0 = 0, w1 = 0;
        if (t == 0 && q < 3) {
            float4 w = *(const float4*)(Wo + 4 * q);
            w0 = h2pack(w.x, w.y);
            w1 = h2pack(w.z, w.w);
        }
        if (t == 0 && q == 3) w0 = h2pack(bo[0], 0.f); // output bias at k=12
        wq[15] = (i32x2){ w0, w1 };
    }

    // ---- per-lane feature offsets (elements): channel c=4q+r at (dy,dx) ----
    const int sh8  = q * 8;
    const int off0 = (int)(signed char)((0x00DCB8B4u >> sh8) & 0xFFu);
    const int off1 = (int)(signed char)((0x00DDD9B5u >> sh8) & 0xFFu);
    const int off2 = (int)(signed char)((0x00FEDAB6u >> sh8) & 0xFFu);
    const int off3 = (int)(signed char)((0x00FFDBB7u >> sh8) & 0xFFu);
    const bool q3  = (q == 3);

    int e = (wv * 8 + 2) * 37 + (t + 2);             // row 8wv, half 0

    float d2 = 0.0f;
    #pragma unroll 1
    for (int yi = 0; yi < 4; ++yi) {
        // chains: A=(row r,half0) B=(r,half1) C=(r+1,half0) D=(r+1,half1)
        // q==3 lanes carry the bias slot: word0 = f16(1.0) at k=12.
        const int faA0 = q3 ? 0x3C00 : h2pack(tile[e + off0],      tile[e + off1]);
        const int faA1 = q3 ? 0      : h2pack(tile[e + off2],      tile[e + off3]);
        const int fbA0 = q3 ? 0x3C00 : h2pack(tile[e + off0 + 16], tile[e + off1 + 16]);
        const int fbA1 = q3 ? 0      : h2pack(tile[e + off2 + 16], tile[e + off3 + 16]);
        const int fcA0 = q3 ? 0x3C00 : h2pack(tile[e + off0 + 37], tile[e + off1 + 37]);
        const int fcA1 = q3 ? 0      : h2pack(tile[e + off2 + 37], tile[e + off3 + 37]);
        const int fdA0 = q3 ? 0x3C00 : h2pack(tile[e + off0 + 53], tile[e + off1 + 53]);
        const int fdA1 = q3 ? 0      : h2pack(tile[e + off2 + 53], tile[e + off3 + 53]);
        const float vA = tile[e], vB = tile[e + 16];
        const float vC = tile[e + 37], vD = tile[e + 53];

        float pA, pB, pC, pD;
        asm volatile(
            "s_mov_b32 s21, 0x211f211f\n"
            "v_mov_b32 v32, 0\n" "v_mov_b32 v33, 0\n"
            "v_mov_b32 v34, 0\n" "v_mov_b32 v35, 0\n"
            "v_mov_b32 v36, %[fa0]\n" "v_mov_b32 v37, %[fa1]\n"
            "v_mov_b32 v38, %[fb0]\n" "v_mov_b32 v39, %[fb1]\n"
            "v_mov_b32 v40, %[fc0]\n" "v_mov_b32 v41, %[fc1]\n"
            "v_mov_b32 v42, %[fd0]\n" "v_mov_b32 v43, %[fd1]\n"
            MFA("w0") MFB("w0") MFC("w0") MFD("w0")
            "s_nop 7\n" "s_nop 7\n" "s_nop 7\n" "s_nop 4\n"
            LAYER("w1")  LAYER("w2")  LAYER("w3")  LAYER("w4")
            LAYER("w5")  LAYER("w6")  LAYER("w7")  LAYER("w8")
            LAYER("w9")  LAYER("w10") LAYER("w11") LAYER("w12")
            LAYER("w13") LAYER("w14") LAYER("w15")
            "v_mov_b32 %[pA], v44\n"
            "s_nop 1\n"
            "v_mov_b32 %[pB], v48\n"
            "s_nop 7\n" "s_nop 7\n"
            "v_mov_b32 %[pC], v52\n"
            "s_nop 3\n"
            "v_mov_b32 %[pD], v56\n"
            : [pA] "=v"(pA), [pB] "=v"(pB), [pC] "=v"(pC), [pD] "=v"(pD)
            : [w0] "a"(wq[0]),  [w1] "a"(wq[1]),  [w2] "a"(wq[2]),
              [w3] "a"(wq[3]),  [w4] "a"(wq[4]),  [w5] "a"(wq[5]),
              [w6] "a"(wq[6]),  [w7] "a"(wq[7]),  [w8] "a"(wq[8]),
              [w9] "a"(wq[9]),  [w10] "a"(wq[10]), [w11] "a"(wq[11]),
              [w12] "a"(wq[12]), [w13] "a"(wq[13]), [w14] "a"(wq[14]),
              [w15] "a"(wq[15]),
              [fa0] "v"(faA0), [fa1] "v"(faA1), [fb0] "v"(fbA0), [fb1] "v"(fbA1),
              [fc0] "v"(fcA0), [fc1] "v"(fcA1), [fd0] "v"(fdA0), [fd1] "v"(fdA1)
            : "s21",
              "v32","v33","v34","v35","v36","v37","v38","v39",
              "v40","v41","v42","v43","v44","v45","v46","v47",
              "v48","v49","v50","v51","v52","v53","v54","v55",
              "v56","v57","v58","v59","v60","v61");

        if (lane < 16) {                   // D row 0 = prediction, lanes 0..15
            const float qA = fminf(fmaxf(pA, -1.0f), 1.0f);
            const float uA = vA - qA + 1.0f;
            const float dA = uA - ((uA < 2.0f) ? 1.0f : 3.0f); // fmod(u,2)-1
            const float qB = fminf(fmaxf(pB, -1.0f), 1.0f);
            const float uB = vB - qB + 1.0f;
            const float dB = uB - ((uB < 2.0f) ? 1.0f : 3.0f);
            const float qC = fminf(fmaxf(pC, -1.0f), 1.0f);
            const float uC = vC - qC + 1.0f;
            const float dC = uC - ((uC < 2.0f) ? 1.0f : 3.0f);
            const float qD = fminf(fmaxf(pD, -1.0f), 1.0f);
            const float uD = vD - qD + 1.0f;
            const float dD = uD - ((uD < 2.0f) ? 1.0f : 3.0f);
            const int r = 2 * yi;
            stage[wv][r * 32 + t]            = dA;
            stage[wv][r * 32 + 16 + t]       = dB;
            stage[wv][(r + 1) * 32 + t]      = dC;
            stage[wv][(r + 1) * 32 + 16 + t] = dD;
            d2 = fmaf(dA, dA, fmaf(dB, dB, fmaf(dC, dC, fmaf(dD, dD, d2))));
        }
        e += 74;                            // two rows
    }

    // ---- coalesced delta store: wave's 256 floats = rows [8wv, 8wv+8) ----
    float* outp = out + 1 + (size_t)n * 1024 + wv * 256;
    #pragma unroll
    for (int j = 0; j < 4; ++j)
        outp[j * 64 + lane] = stage[wv][j * 64 + lane];

    // ---- loss reduction (d2 nonzero only in lanes 0..15) ----
    #pragma unroll
    for (int off = 8; off > 0; off >>= 1) d2 += __shfl_down(d2, off, 64);
    if (lane == 0) wsum[wv] = d2;
    __syncthreads();
    if (tid == 0) atomicAdd(loss_acc, wsum[0] + wsum[1] + wsum[2] + wsum[3]);
}

__global__ void codec_loss(const float* __restrict__ acc, float* __restrict__ out)
{
    out[0] = 255.0f * sqrtf(acc[0] / (float)NPIX);
}

extern "C" void kernel_launch(void* const* d_in, const int* in_sizes, int n_in,
                              void* d_out, int out_size, void* d_ws, size_t ws_size,
                              hipStream_t stream)
{
    const float* x  = (const float*)d_in[0];
    const float* Wh = (const float*)d_in[1];
    const float* bh = (const float*)d_in[2];
    const float* Wo = (const float*)d_in[3];
    const float* bo = (const float*)d_in[4];
    float* out = (float*)d_out;
    float* acc = (float*)d_ws;

    hipMemsetAsync(acc, 0, sizeof(float), stream);   // graph-capture safe
    codec_main<<<NBLK, 256, 0, stream>>>(x, Wh, bh, Wo, bo, out, acc);
    codec_loss<<<1, 1, 0, stream>>>(acc, out);
}